// Round 3
// baseline (793.453 us; speedup 1.0000x reference)
//
#include <hip/hip_runtime.h>
#include <cstdint>
#include <cstddef>

namespace {

constexpr int B_ = 1024;
constexpr int T_ = 512;
constexpr int H_ = 64;
constexpr int NG = 64;            // batch groups (16 rows each)

constexpr float L2E  = 1.4426950408889634f;   // log2(e)

typedef short bf16x8 __attribute__((ext_vector_type(8)));
typedef float f32x4  __attribute__((ext_vector_type(4)));

// hardware exp2 / rcp (pure, CSE-able; ~1 ulp — far inside the 2.2e-3 budget)
__device__ __forceinline__ float exp2_hw(float x) {
    float r; asm("v_exp_f32 %0, %1" : "=v"(r) : "v"(x)); return r;
}
__device__ __forceinline__ float rcp_hw(float x) {
    float r; asm("v_rcp_f32 %0, %1" : "=v"(r) : "v"(x)); return r;
}

__device__ __forceinline__ unsigned short f2bf(float f) {   // RNE fp32 -> bf16
    unsigned u = __float_as_uint(f);
    u += 0x7FFF + ((u >> 16) & 1);
    return (unsigned short)(u >> 16);
}

// packed RNE fp32x2 -> bf16x2 (low = a, high = b)
__device__ __forceinline__ unsigned cvtpk_bf16(float a, float b) {
    unsigned r;
    asm("v_cvt_pk_bf16_f32 %0, %1, %2" : "=v"(r) : "v"(a), "v"(b));
    return r;
}

// LDS-only barrier: does NOT drain vmcnt — x prefetch stays in flight.
__device__ __forceinline__ void lds_barrier() {
    asm volatile("s_waitcnt lgkmcnt(0)\n\ts_barrier" ::: "memory");
}

// ---------------------------------------------------------------------------
// Setup kernels.  Weights/biases are PRE-SCALED: gate rows i,f,o by log2(e),
// g rows (block 2: rows 128..191) by 2*log2(e), so the cell update uses raw
// v_exp_f32 (exp2) with no per-element scaling:
//   sigmoid(x) = rcp(1 + exp2(-x'))            x' = L2E*x
//   tanh(x)    = 2*rcp(1 + exp2(-x'')) - 1     x'' = 2*L2E*x
// ---------------------------------------------------------------------------

// [256][64] fp32 -> bf16, row-dependent scale
__global__ void cvt_bf16_kernel(const float* __restrict__ src,
                                unsigned short* __restrict__ dst, int n) {
    int i = blockIdx.x * 256 + threadIdx.x;
    if (i < n) {
        int row = i >> 6;                       // gate row 0..255
        float sc = ((row >> 6) == 2) ? 2.0f * L2E : L2E;
        dst[i] = f2bf(src[i] * sc);
    }
}

// wih0: [256][6] fp32 -> [256][8] bf16 (k=6,7 zero), scaled
__global__ void cvt_wih0_kernel(const float* __restrict__ src,
                                unsigned short* __restrict__ dst) {
    int i = blockIdx.x * 256 + threadIdx.x;   // 2048
    int g = i >> 3, k = i & 7;
    float sc = ((g >> 6) == 2) ? 2.0f * L2E : L2E;
    dst[i] = (k < 6) ? f2bf(src[g * 6 + k] * sc) : (unsigned short)0;
}

// xPk[t][g][r16][k8] bf16: L0's A-frag-ready x (k 0..5 valid, 6,7 zero)
__global__ void build_xpk(const float* __restrict__ x,
                          unsigned short* __restrict__ xPk) {
    int idx = blockIdx.x * 256 + threadIdx.x;   // T*NG*16*8 = 4.19M
    int k = idx & 7, r = (idx >> 3) & 15, g = (idx >> 7) & 63, t = idx >> 13;
    float v = (k < 6) ? x[((size_t)(g * 16 + r) * T_ + t) * 6 + k] : 0.f;
    xPk[idx] = f2bf(v);
}

// ---------------------------------------------------------------------------
// FUSED 3-layer LSTM. One block = one batch group (64 blocks, 256 threads,
// 4 waves; wave w owns hdim block [16w,16w+16), lane: r16=l&15, kq=l>>4 —
// identical per-layer decomposition to the proven 3-block pipeline).
//
// Software pipeline within the block, iteration i (i = 0 .. T+1):
//   L0 (i<T):        reads h0[i-1]  (tile H0[p^1]), x[i] (global prefetch)
//                    writes h0[i]   -> H0[p]
//   L1 (1<=i<=T):    reads h0[i-1]  (H0[p^1], written iter i-1)
//                    reads h1[i-2]  (H1[p^1]), writes h1[i-1] -> H1[p]
//   L2 (2<=i<=T+1):  reads h1[i-2]  (H1[p^1]), h2[i-3] (H2[p^1])
//                    writes h2[i-2] -> H2[p]  (i==T+1: h2[T-1] -> hlast)
// Every tile read at iter i was written at iter i-1 -> ONE lds_barrier per
// iteration (parity double-buffer). NO inter-block communication: no ring,
// no flags, no sc0sc1, no manual vmcnt. The only global loads in the loop
// are L0's x rows (plain C++ loads; compiler inserts the vmcnt before use,
// pure-load queue -> in-order semantics are trivially safe).
// ---------------------------------------------------------------------------
__global__ __launch_bounds__(256, 1)
void lstm_fused(const unsigned short* __restrict__ xPk,
                const unsigned short* __restrict__ wih0p,
                const unsigned short* __restrict__ wih1,
                const unsigned short* __restrict__ wih2,
                const unsigned short* __restrict__ whh0,
                const unsigned short* __restrict__ whh1,
                const unsigned short* __restrict__ whh2,
                const float* __restrict__ bih0, const float* __restrict__ bhh0,
                const float* __restrict__ bih1, const float* __restrict__ bhh1,
                const float* __restrict__ bih2, const float* __restrict__ bhh2,
                float* __restrict__ hlast)
{
    __shared__ unsigned short lds[6][1024];   // H0[2],H1[2],H2[2]: 12 KiB

    const int g   = blockIdx.x;
    const int tid = threadIdx.x;
    const int l   = tid & 63;
    const int w   = tid >> 6;
    const int r16 = l & 15;
    const int kq  = l >> 4;
    const int hdim = w * 16 + r16;

    // ---- weight fragments, 3 layers (B-frag: col=l&15 -> gate row) ----
    bf16x8 w0h[4][2], w0x[4];
    bf16x8 w1h[4][2], w1x[4][2];
    bf16x8 w2h[4][2], w2x[4][2];
    f32x4  b0[4], b1[4], b2[4];
    #pragma unroll
    for (int d = 0; d < 4; ++d) {
        const int gg = d * 64 + hdim;
        const float sc = (d == 2) ? 2.0f * L2E : L2E;
        const float v0 = (bih0[gg] + bhh0[gg]) * sc;
        const float v1 = (bih1[gg] + bhh1[gg]) * sc;
        const float v2 = (bih2[gg] + bhh2[gg]) * sc;
        b0[d] = f32x4{v0, v0, v0, v0};
        b1[d] = f32x4{v1, v1, v1, v1};
        b2[d] = f32x4{v2, v2, v2, v2};
        w0h[d][0] = *(const bf16x8*)(whh0 + gg * 64 + kq * 8);
        w0h[d][1] = *(const bf16x8*)(whh0 + gg * 64 + 32 + kq * 8);
        w1h[d][0] = *(const bf16x8*)(whh1 + gg * 64 + kq * 8);
        w1h[d][1] = *(const bf16x8*)(whh1 + gg * 64 + 32 + kq * 8);
        w2h[d][0] = *(const bf16x8*)(whh2 + gg * 64 + kq * 8);
        w2h[d][1] = *(const bf16x8*)(whh2 + gg * 64 + 32 + kq * 8);
        {   // L0 x-weights: [256][8], only kq==0 lanes carry data
            bf16x8 z = {};
            w0x[d] = (kq == 0) ? *(const bf16x8*)(wih0p + gg * 8) : z;
        }
        w1x[d][0] = *(const bf16x8*)(wih1 + gg * 64 + kq * 8);
        w1x[d][1] = *(const bf16x8*)(wih1 + gg * 64 + 32 + kq * 8);
        w2x[d][0] = *(const bf16x8*)(wih2 + gg * 64 + kq * 8);
        w2x[d][1] = *(const bf16x8*)(wih2 + gg * 64 + 32 + kq * 8);
    }

    // ---- LDS addressing (XOR swizzle, verified r4-r9 / baseline) ----
    char* ldsb = (char*)lds;
    const int rdA0 = r16 * 128 + (((0 + kq) ^ (r16 & 7)) << 4);
    const int rdA1 = r16 * 128 + (((4 + kq) ^ (r16 & 7)) << 4);
    int wrA[4];
    #pragma unroll
    for (int r = 0; r < 4; ++r) {
        const int row = 4 * kq + r;
        wrA[r] = row * 128 + (((hdim >> 3) ^ (row & 7)) << 4) + (hdim & 7) * 2;
    }
    auto tile = [&](int layer, int p) -> char* {
        return ldsb + (size_t)(layer * 2 + p) * 2048;
    };

    // ---- zero all tiles (h[-1] = 0 for all layers / both parities) ----
    {
        uint4* z = (uint4*)ldsb;      // 12288 B = 768 x 16 B
        z[tid] = make_uint4(0, 0, 0, 0);
        z[tid + 256] = make_uint4(0, 0, 0, 0);
        z[tid + 512] = make_uint4(0, 0, 0, 0);
    }
    float c0[4] = {0.f, 0.f, 0.f, 0.f};
    float c1[4] = {0.f, 0.f, 0.f, 0.f};
    float c2[4] = {0.f, 0.f, 0.f, 0.f};
    lds_barrier();

    // ---- x prefetch (plain loads; lanes sharing r16 read the same 16B) ----
    constexpr size_t XSTEP = (size_t)NG * 16 * 16;   // bytes per t (16 KiB)
    const char* xp0 = (const char*)xPk + ((size_t)g * 16 + r16) * 16;
    const char* xpA = xp0;                // even t
    const char* xpB = xp0 + XSTEP;        // odd t
    bf16x8 curA = *(const bf16x8*)xpA;    // x[0]
    bf16x8 curB = *(const bf16x8*)xpB;    // x[1]

    // ---- cell update (identical math to proven baseline) ----
    auto cell_core = [&](const f32x4* acc, float* c, float* h) {
        #pragma unroll
        for (int r = 0; r < 4; ++r) {
            const float gi = acc[0][r], gf = acc[1][r], gg = acc[2][r], go = acc[3][r];
            const float si = rcp_hw(1.0f + exp2_hw(-gi));
            const float sf = rcp_hw(1.0f + exp2_hw(-gf));
            const float so = rcp_hw(1.0f + exp2_hw(-go));
            const float tg = __builtin_fmaf(2.0f, rcp_hw(1.0f + exp2_hw(-gg)), -1.0f);
            c[r] = sf * c[r] + si * tg;
            const float tc = __builtin_fmaf(2.0f, rcp_hw(1.0f + exp2_hw(c[r] * (-2.0f * L2E))), -1.0f);
            h[r] = so * tc;
        }
    };
    auto cell_write = [&](const f32x4* acc, float* c, char* wbase) {
        float h[4];
        cell_core(acc, c, h);
        const unsigned p01 = cvtpk_bf16(h[0], h[1]);
        const unsigned p23 = cvtpk_bf16(h[2], h[3]);
        *(unsigned short*)(wbase + wrA[0]) = (unsigned short)(p01 & 0xffff);
        *(unsigned short*)(wbase + wrA[1]) = (unsigned short)(p01 >> 16);
        *(unsigned short*)(wbase + wrA[2]) = (unsigned short)(p23 & 0xffff);
        *(unsigned short*)(wbase + wrA[3]) = (unsigned short)(p23 >> 16);
    };

    // ---- layer bodies ----
    auto L0_body = [&](int P, const bf16x8& curX) {
        const bf16x8 ha = *(const bf16x8*)(tile(0, P ^ 1) + rdA0);
        const bf16x8 hb = *(const bf16x8*)(tile(0, P ^ 1) + rdA1);
        f32x4 acc[4];
        #pragma unroll
        for (int d = 0; d < 4; ++d) {
            acc[d] = __builtin_amdgcn_mfma_f32_16x16x32_bf16(curX, w0x[d], b0[d], 0, 0, 0);
            acc[d] = __builtin_amdgcn_mfma_f32_16x16x32_bf16(ha, w0h[d][0], acc[d], 0, 0, 0);
            acc[d] = __builtin_amdgcn_mfma_f32_16x16x32_bf16(hb, w0h[d][1], acc[d], 0, 0, 0);
        }
        cell_write(acc, c0, tile(0, P));
    };
    auto L1_body = [&](int P) {
        const bf16x8 xa = *(const bf16x8*)(tile(0, P ^ 1) + rdA0);
        const bf16x8 xb = *(const bf16x8*)(tile(0, P ^ 1) + rdA1);
        const bf16x8 ha = *(const bf16x8*)(tile(1, P ^ 1) + rdA0);
        const bf16x8 hb = *(const bf16x8*)(tile(1, P ^ 1) + rdA1);
        f32x4 acc[4];
        #pragma unroll
        for (int d = 0; d < 4; ++d) {
            acc[d] = __builtin_amdgcn_mfma_f32_16x16x32_bf16(xa, w1x[d][0], b1[d], 0, 0, 0);
            acc[d] = __builtin_amdgcn_mfma_f32_16x16x32_bf16(xb, w1x[d][1], acc[d], 0, 0, 0);
            acc[d] = __builtin_amdgcn_mfma_f32_16x16x32_bf16(ha, w1h[d][0], acc[d], 0, 0, 0);
            acc[d] = __builtin_amdgcn_mfma_f32_16x16x32_bf16(hb, w1h[d][1], acc[d], 0, 0, 0);
        }
        cell_write(acc, c1, tile(1, P));
    };
    auto L2_body = [&](int P, bool last) {
        const bf16x8 xa = *(const bf16x8*)(tile(1, P ^ 1) + rdA0);
        const bf16x8 xb = *(const bf16x8*)(tile(1, P ^ 1) + rdA1);
        const bf16x8 ha = *(const bf16x8*)(tile(2, P ^ 1) + rdA0);
        const bf16x8 hb = *(const bf16x8*)(tile(2, P ^ 1) + rdA1);
        f32x4 acc[4];
        #pragma unroll
        for (int d = 0; d < 4; ++d) {
            acc[d] = __builtin_amdgcn_mfma_f32_16x16x32_bf16(xa, w2x[d][0], b2[d], 0, 0, 0);
            acc[d] = __builtin_amdgcn_mfma_f32_16x16x32_bf16(xb, w2x[d][1], acc[d], 0, 0, 0);
            acc[d] = __builtin_amdgcn_mfma_f32_16x16x32_bf16(ha, w2h[d][0], acc[d], 0, 0, 0);
            acc[d] = __builtin_amdgcn_mfma_f32_16x16x32_bf16(hb, w2h[d][1], acc[d], 0, 0, 0);
        }
        if (last) {
            float h[4];
            cell_core(acc, c2, h);
            #pragma unroll
            for (int r = 0; r < 4; ++r)
                hlast[(g * 16 + kq * 4 + r) * 64 + hdim] = h[r];
        } else {
            cell_write(acc, c2, tile(2, P));
        }
    };

    // ---- one pipeline iteration ----
    auto do_iter = [&](int i, int P, bf16x8& curX, const char*& xp) {
        if (i >= 2 && i < T_) {
            // steady state: one scheduling region, three independent chains
            L0_body(P, curX);
            if (i + 2 < T_) { xp += 2 * XSTEP; curX = *(const bf16x8*)xp; }
            L1_body(P);
            L2_body(P, false);
        } else {
            if (i < T_) {
                L0_body(P, curX);
                if (i + 2 < T_) { xp += 2 * XSTEP; curX = *(const bf16x8*)xp; }
            }
            if (i >= 1 && i <= T_) L1_body(P);
            if (i >= 2) L2_body(P, i == T_ + 1);
        }
        lds_barrier();
    };

    #pragma unroll 1
    for (int i = 0; i < T_ + 2; i += 2) {
        do_iter(i,     0, curA, xpA);
        do_iter(i + 1, 1, curB, xpB);
    }
}

// ---------------------------------------------------------------------------
// MLP head: one block per batch row. 64 -> 128 relu -> 64 relu -> 2.
// ---------------------------------------------------------------------------
__global__ __launch_bounds__(128)
void mlp_head_kernel(const float* __restrict__ hlast,
                     const float* __restrict__ fc1_w, const float* __restrict__ fc1_b,
                     const float* __restrict__ fc3_w, const float* __restrict__ fc3_b,
                     const float* __restrict__ fc2_w, const float* __restrict__ fc2_b,
                     float* __restrict__ outp)
{
    __shared__ float s_h[H_];
    __shared__ float s_z1[128];
    __shared__ float s_z3[64];
    const int b = blockIdx.x, tid = threadIdx.x;

    if (tid < H_) s_h[tid] = hlast[b * H_ + tid];
    __syncthreads();

    {
        float acc = fc1_b[tid];
        #pragma unroll
        for (int k = 0; k < H_; ++k) acc += fc1_w[tid * H_ + k] * s_h[k];
        s_z1[tid] = fmaxf(acc, 0.0f);
    }
    __syncthreads();

    if (tid < 64) {
        float acc = fc3_b[tid];
        #pragma unroll
        for (int k = 0; k < 128; ++k) acc += fc3_w[tid * 128 + k] * s_z1[k];
        s_z3[tid] = fmaxf(acc, 0.0f);
    }
    __syncthreads();

    if (tid < 2) {
        float acc = fc2_b[tid];
        #pragma unroll
        for (int k = 0; k < 64; ++k) acc += fc2_w[tid * 64 + k] * s_z3[k];
        outp[b * 2 + tid] = acc;
    }
}

} // namespace

extern "C" void kernel_launch(void* const* d_in, const int* in_sizes, int n_in,
                              void* d_out, int out_size, void* d_ws, size_t ws_size,
                              hipStream_t stream) {
    (void)in_sizes; (void)n_in; (void)out_size; (void)ws_size;

    const float* x     = (const float*)d_in[0];
    const float* wih0  = (const float*)d_in[1];
    const float* whh0  = (const float*)d_in[2];
    const float* bih0  = (const float*)d_in[3];
    const float* bhh0  = (const float*)d_in[4];
    const float* wih1  = (const float*)d_in[5];
    const float* whh1  = (const float*)d_in[6];
    const float* bih1  = (const float*)d_in[7];
    const float* bhh1  = (const float*)d_in[8];
    const float* wih2  = (const float*)d_in[9];
    const float* whh2  = (const float*)d_in[10];
    const float* bih2  = (const float*)d_in[11];
    const float* bhh2  = (const float*)d_in[12];
    const float* fc1_w = (const float*)d_in[13];
    const float* fc1_b = (const float*)d_in[14];
    const float* fc3_w = (const float*)d_in[15];
    const float* fc3_b = (const float*)d_in[16];
    const float* fc2_w = (const float*)d_in[17];
    const float* fc2_b = (const float*)d_in[18];
    float* out = (float*)d_out;

    // ---- workspace layout ----
    char* base = (char*)d_ws;
    const size_t XPK_B = (size_t)T_ * NG * 16 * 8 * 2;              // 8 MiB
    unsigned short* xPk  = (unsigned short*)base;
    float*          hlast = (float*)(base + XPK_B);
    char* wp = base + XPK_B + (size_t)B_ * H_ * 4;
    unsigned short* whh_b[3];
    for (int i = 0; i < 3; ++i) { whh_b[i] = (unsigned short*)wp; wp += 256 * 64 * 2; }
    unsigned short* wih_b1 = (unsigned short*)wp; wp += 256 * 64 * 2;
    unsigned short* wih_b2 = (unsigned short*)wp; wp += 256 * 64 * 2;
    unsigned short* wih0p  = (unsigned short*)wp; wp += 256 * 8 * 2;

    // ---- setup: weights (pre-scaled), packed x ----
    const int NW = 256 * 64;
    cvt_bf16_kernel<<<NW / 256, 256, 0, stream>>>(whh0, whh_b[0], NW);
    cvt_bf16_kernel<<<NW / 256, 256, 0, stream>>>(whh1, whh_b[1], NW);
    cvt_bf16_kernel<<<NW / 256, 256, 0, stream>>>(whh2, whh_b[2], NW);
    cvt_bf16_kernel<<<NW / 256, 256, 0, stream>>>(wih1, wih_b1, NW);
    cvt_bf16_kernel<<<NW / 256, 256, 0, stream>>>(wih2, wih_b2, NW);
    cvt_wih0_kernel<<<8, 256, 0, stream>>>(wih0, wih0p);
    build_xpk<<<(T_ * NG * 16 * 8) / 256, 256, 0, stream>>>(x, xPk);

    // ---- fused 3-layer LSTM: 64 blocks (one per batch group) ----
    lstm_fused<<<64, 256, 0, stream>>>(xPk, wih0p, wih_b1, wih_b2,
                                       whh_b[0], whh_b[1], whh_b[2],
                                       bih0, bhh0, bih1, bhh1, bih2, bhh2,
                                       hlast);

    // ---- MLP head ----
    mlp_head_kernel<<<B_, 128, 0, stream>>>(hlast, fc1_w, fc1_b, fc3_w, fc3_b,
                                            fc2_w, fc2_b, out);
}

// Round 5
// 386.020 us; speedup vs baseline: 2.0555x; 2.0555x over previous
//
#include <hip/hip_runtime.h>
#include <cstdint>
#include <cstddef>

namespace {

constexpr int B_ = 1024;
constexpr int T_ = 512;
constexpr int H_ = 64;
constexpr int NG = 64;            // batch groups (16 rows each)
constexpr int D_RING = 64;        // ring depth in steps
constexpr int CP = 16;            // poll/publish chunk (baseline-proven)
constexpr int SLOT_BYTES = 16 * 64 * 2;   // one h-tile: [16 rows][64 hd] bf16

constexpr float L2E  = 1.4426950408889634f;   // log2(e)

typedef short bf16x8 __attribute__((ext_vector_type(8)));
typedef float f32x4  __attribute__((ext_vector_type(4)));

// hardware exp2 / rcp (pure, CSE-able; ~1 ulp — far inside the 2.2e-3 budget)
__device__ __forceinline__ float exp2_hw(float x) {
    float r; asm("v_exp_f32 %0, %1" : "=v"(r) : "v"(x)); return r;
}
__device__ __forceinline__ float rcp_hw(float x) {
    float r; asm("v_rcp_f32 %0, %1" : "=v"(r) : "v"(x)); return r;
}

__device__ __forceinline__ unsigned short f2bf(float f) {   // RNE fp32 -> bf16
    unsigned u = __float_as_uint(f);
    u += 0x7FFF + ((u >> 16) & 1);
    return (unsigned short)(u >> 16);
}

// packed RNE fp32x2 -> bf16x2 (low = a, high = b)
__device__ __forceinline__ unsigned cvtpk_bf16(float a, float b) {
    unsigned r;
    asm("v_cvt_pk_bf16_f32 %0, %1, %2" : "=v"(r) : "v"(a), "v"(b));
    return r;
}

// LDS-only barrier: does NOT drain vmcnt — global ops stay in flight.
__device__ __forceinline__ void lds_barrier() {
    asm volatile("s_waitcnt lgkmcnt(0)\n\ts_barrier" ::: "memory");
}

// device-coherent (sc0 sc1) 16B store: write-through -> LLC-visible
__device__ __forceinline__ void ring_store16(void* dst, bf16x8 v) {
    asm volatile("global_store_dwordx4 %0, %1, off sc0 sc1"
                 :: "v"(dst), "v"(v) : "memory");
}
// coherent flag load (bypasses stale L2) — BLOCKING
__device__ __forceinline__ int flag_load(const int* p) {
    int v;
    asm volatile("global_load_dword %0, %1, off sc0 sc1\n\t"
                 "s_waitcnt vmcnt(0)" : "=v"(v) : "v"(p) : "memory");
    return v;
}
// release flag store: drain own stores, then coherent store (producers only)
__device__ __forceinline__ void flag_store_drain(int* p, int v) {
    asm volatile("s_waitcnt vmcnt(0)\n\t"
                 "global_store_dword %0, %1, off sc0 sc1"
                 :: "v"(p), "v"(v) : "memory");
}
// plain coherent flag store (consumption progress: no drain needed)
__device__ __forceinline__ void flag_store(int* p, int v) {
    asm volatile("global_store_dword %0, %1, off sc0 sc1"
                 :: "v"(p), "v"(v) : "memory");
}
__device__ __forceinline__ void spin_ge(const int* p, int tgt) {
    while (flag_load(p) < tgt) __builtin_amdgcn_s_sleep(1);
}

// ---------------------------------------------------------------------------
// Setup kernels.  Weights/biases are PRE-SCALED: gate rows i,f,o by log2(e),
// g rows (block 2: rows 128..191) by 2*log2(e), so the cell update uses raw
// v_exp_f32 (exp2) with no per-element scaling:
//   sigmoid(x) = rcp(1 + exp2(-x'))            x' = L2E*x
//   tanh(x)    = 2*rcp(1 + exp2(-x'')) - 1     x'' = 2*L2E*x
// ---------------------------------------------------------------------------
__global__ void init_flags(int* p, int n) {
    int i = blockIdx.x * 256 + threadIdx.x;
    if (i < n) p[i] = -1;
}

// [256][64] fp32 -> bf16, row-dependent scale
__global__ void cvt_bf16_kernel(const float* __restrict__ src,
                                unsigned short* __restrict__ dst, int n) {
    int i = blockIdx.x * 256 + threadIdx.x;
    if (i < n) {
        int row = i >> 6;                       // gate row 0..255
        float sc = ((row >> 6) == 2) ? 2.0f * L2E : L2E;
        dst[i] = f2bf(src[i] * sc);
    }
}

// wih0: [256][6] fp32 -> [256][8] bf16 (k=6,7 zero), scaled
__global__ void cvt_wih0_kernel(const float* __restrict__ src,
                                unsigned short* __restrict__ dst) {
    int i = blockIdx.x * 256 + threadIdx.x;   // 2048
    int g = i >> 3, k = i & 7;
    float sc = ((g >> 6) == 2) ? 2.0f * L2E : L2E;
    dst[i] = (k < 6) ? f2bf(src[g * 6 + k] * sc) : (unsigned short)0;
}

// xPk[t][g][r16][k8] bf16: L0's A-frag-ready x (k 0..5 valid, 6,7 zero)
__global__ void build_xpk(const float* __restrict__ x,
                          unsigned short* __restrict__ xPk) {
    int idx = blockIdx.x * 256 + threadIdx.x;   // T*NG*16*8 = 4.19M
    int k = idx & 7, r = (idx >> 3) & 15, g = (idx >> 7) & 63, t = idx >> 13;
    float v = (k < 6) ? x[((size_t)(g * 16 + r) * T_ + t) * 6 + k] : 0.f;
    xPk[idx] = f2bf(v);
}

// ---------------------------------------------------------------------------
// Pipelined LSTM body (baseline 192-block structure, flag protocol UNCHANGED
// from the 393us harness-verified kernel). One block = (layer LAY, group g),
// 4 waves. Wave w owns hdim block [16w,16w+16); lane: r16=l&15, kq=l>>4.
//
// ONLY change vs baseline: LAY>0 x-ring prefetch depth 2 -> 3 (sc0sc1 loads
// bypass L2 -> LLC latency ~500-900cy; depth-2 gave ~600cy of hiding, depth-3
// gives ~2300cy). Parity register sets: loads issued at step t (parity p)
// land in cur{A,B} of parity p and are consumed at step t+2 (same parity),
// drained by that step's counted wait — the same in-flight-register pattern
// the baseline already proves safe at depth 2.
//
// Wait-count derivation (in-order vmcnt, the baseline's proven assumption):
//  LAY0 (depth 2, unchanged): w0 vmcnt(2) [skips own 2 young ring stores],
//    others vmcnt(0).
//  LAY1 (depth 3): per step w0 issues R2 (x(t+3)) then S2 (h(t-1)). At step
//    t's wait, ops younger than the needed R(x(t+1))@t-2: S2@t-2, R2@t-1,
//    S2@t-1 = 6 -> w0 vmcnt(6). Non-w0: pure loads, younger = R2@t-1 ->
//    vmcnt(2).
//  LAY2 (depth 3, no stores): vmcnt(2) all waves.
//  Last 4 steps peeled with vmcnt(0) (load issue stops at s>=T, counted
//  waits would under-wait).
// ---------------------------------------------------------------------------
template<int LAY>
__device__ __forceinline__ void pipe_body(
    int g,
    const unsigned short* __restrict__ xPk,
    const unsigned short* __restrict__ wih,
    const unsigned short* __restrict__ whh,
    const float* __restrict__ bih, const float* __restrict__ bhh,
    const unsigned short* __restrict__ ringIn, unsigned short* __restrict__ ringOut,
    const int* progIn, int* progOut, int* consInP, const int* consOutP,
    float* __restrict__ hlast, unsigned short* lds)
{
    const int tid = threadIdx.x;
    const int l   = tid & 63;
    const int w   = tid >> 6;
    const int r16 = l & 15;
    const int kq  = l >> 4;
    const int hdim = w * 16 + r16;

    // ---- weight fragments (B-frag: col=l&15 -> gate row, k=8*kq+i) ----
    bf16x8 whh_f[4][2], wih_f[4][2];
    f32x4  bias_acc[4];
    #pragma unroll
    for (int d = 0; d < 4; ++d) {
        const int gg = d * 64 + hdim;
        const float sc = (d == 2) ? 2.0f * L2E : L2E;
        const float b = (bih[gg] + bhh[gg]) * sc;
        bias_acc[d] = f32x4{b, b, b, b};
        whh_f[d][0] = *(const bf16x8*)(whh + gg * 64 + kq * 8);
        whh_f[d][1] = *(const bf16x8*)(whh + gg * 64 + 32 + kq * 8);
        if constexpr (LAY == 0) {
            bf16x8 z = {};
            wih_f[d][0] = (kq == 0) ? *(const bf16x8*)(wih + gg * 8) : z;
            wih_f[d][1] = z;
        } else {
            wih_f[d][0] = *(const bf16x8*)(wih + gg * 64 + kq * 8);
            wih_f[d][1] = *(const bf16x8*)(wih + gg * 64 + 32 + kq * 8);
        }
    }

    // ---- LDS addressing (XOR swizzle, verified r4-r9) ----
    char* ldsb = (char*)lds;
    const int rdA0 = r16 * 128 + (((0 + kq) ^ (r16 & 7)) << 4);
    const int rdA1 = r16 * 128 + (((4 + kq) ^ (r16 & 7)) << 4);
    int wrA[4];
    #pragma unroll
    for (int r = 0; r < 4; ++r) {
        const int row = 4 * kq + r;
        wrA[r] = row * 128 + (((hdim >> 3) ^ (row & 7)) << 4) + (hdim & 7) * 2;
    }
    // ring lane offsets (linear row-major inside a slot)
    const int rOffA = r16 * 128 + kq * 16;
    const int rOffB = r16 * 128 + 64 + kq * 16;

    // L0 xPk row address (wave-wide; lanes sharing r16 read the same 16B)
    auto xrow = [&](int t) -> const char* {
        return (const char*)xPk + (((size_t)t * NG + g) * 16 + r16) * 16;
    };

    // ---- zero LDS (h[-1]=0), init cell state ----
    ((uint4*)ldsb)[tid] = make_uint4(0, 0, 0, 0);   // 256*16B = 4 KiB
    float c[4] = {0.f, 0.f, 0.f, 0.f};
    lds_barrier();

    // ---- ramp ----
    // LAY0: x(0) blocking into x0a; x(1) blocking into cur0 (depth-2 as
    // baseline). LAY>0: slots 0,1,2 blocking into x0*, curA*, curB*.
    bf16x8 cur0 = {};                       // LAY0 x register
    bf16x8 curA0 = {}, curA1 = {};          // LAY>0 parity-0 x regs
    bf16x8 curB0 = {}, curB1 = {};          // LAY>0 parity-1 x regs
    f32x4 accA[4], accB[4];
    {
        bf16x8 x0a = {}, x0b = {};
        if constexpr (LAY > 0) {
            spin_ge(progIn, (CP - 1 < T_ - 1) ? CP - 1 : T_ - 1);
            const char* s0 = (const char*)ringIn;                     // slot 0
            const char* s1 = (const char*)ringIn + SLOT_BYTES;        // slot 1
            const char* s2 = (const char*)ringIn + 2 * SLOT_BYTES;    // slot 2
            asm volatile(
                "global_load_dwordx4 %0, %6, off sc0 sc1\n\t"
                "global_load_dwordx4 %1, %7, off sc0 sc1\n\t"
                "global_load_dwordx4 %2, %8, off sc0 sc1\n\t"
                "global_load_dwordx4 %3, %9, off sc0 sc1\n\t"
                "global_load_dwordx4 %4, %10, off sc0 sc1\n\t"
                "global_load_dwordx4 %5, %11, off sc0 sc1\n\t"
                "s_waitcnt vmcnt(0)"
                : "=v"(x0a), "=v"(x0b), "=v"(curA0), "=v"(curA1),
                  "=v"(curB0), "=v"(curB1)
                : "v"(s0 + rOffA), "v"(s0 + rOffB),
                  "v"(s1 + rOffA), "v"(s1 + rOffB),
                  "v"(s2 + rOffA), "v"(s2 + rOffB)
                : "memory");
            __builtin_amdgcn_sched_barrier(0);
        } else {
            asm volatile(
                "global_load_dwordx4 %0, %2, off\n\t"
                "global_load_dwordx4 %1, %3, off\n\t"
                "s_waitcnt vmcnt(0)"
                : "=v"(x0a), "=v"(cur0)
                : "v"(xrow(0)), "v"(xrow(1))
                : "memory");
            __builtin_amdgcn_sched_barrier(0);
        }
        #pragma unroll
        for (int d = 0; d < 4; ++d) {
            accA[d] = __builtin_amdgcn_mfma_f32_16x16x32_bf16(x0a, wih_f[d][0], bias_acc[d], 0, 0, 0);
            if constexpr (LAY != 0)
                accA[d] = __builtin_amdgcn_mfma_f32_16x16x32_bf16(x0b, wih_f[d][1], accA[d], 0, 0, 0);
        }
    }

    // ---- one step. cp0/cp1 = this parity's x regs (LAY>0): consumed at the
    // wait (value loaded 2 steps ago), then reloaded with s=t+3. ----
    auto step = [&](int t, int par, bool tail, f32x4* accC, f32x4* accN,
                    bf16x8& cp0, bf16x8& cp1) {
        // producer backpressure (chunk edge; baseline-identical)
        if constexpr (LAY < 2) {
            if ((t & (CP - 1)) == 0) spin_ge(consOutP, t + CP - D_RING);
        }
        // early publish (baseline-identical: drained release, cadence 16)
        if constexpr (LAY < 2) {
            if ((t & (CP - 1)) == 1 && t > 1) {
                if (tid == 0) flag_store_drain(progOut, t - 2);
            }
        }

        // h[t-1] A-frags from LDS
        const bf16x8 ha = *(const bf16x8*)(ldsb + ((par ^ 1) << 11) + rdA0);
        const bf16x8 hb = *(const bf16x8*)(ldsb + ((par ^ 1) << 11) + rdA1);

        // h-part MFMAs (critical chain)
        #pragma unroll
        for (int d = 0; d < 4; ++d) {
            accC[d] = __builtin_amdgcn_mfma_f32_16x16x32_bf16(ha, whh_f[d][0], accC[d], 0, 0, 0);
            accC[d] = __builtin_amdgcn_mfma_f32_16x16x32_bf16(hb, whh_f[d][1], accC[d], 0, 0, 0);
        }

        // wait for x(t+1) regs (see header derivation)
        if (tail) {
            asm volatile("s_waitcnt vmcnt(0)" ::: "memory");
        } else if constexpr (LAY == 0) {
            if (w == 0) asm volatile("s_waitcnt vmcnt(2)" ::: "memory");
            else        asm volatile("s_waitcnt vmcnt(0)" ::: "memory");
        } else if constexpr (LAY == 1) {
            if (w == 0) asm volatile("s_waitcnt vmcnt(6)" ::: "memory");
            else        asm volatile("s_waitcnt vmcnt(2)" ::: "memory");
        } else {
            asm volatile("s_waitcnt vmcnt(2)" ::: "memory");
        }
        __builtin_amdgcn_sched_barrier(0);

        // x-part of t+1 into accN (off-chain; overlaps cell update)
        if (t + 1 < T_) {
            if constexpr (LAY == 0) {
                #pragma unroll
                for (int d = 0; d < 4; ++d)
                    accN[d] = __builtin_amdgcn_mfma_f32_16x16x32_bf16(cur0, wih_f[d][0], bias_acc[d], 0, 0, 0);
            } else {
                #pragma unroll
                for (int d = 0; d < 4; ++d) {
                    accN[d] = __builtin_amdgcn_mfma_f32_16x16x32_bf16(cp0, wih_f[d][0], bias_acc[d], 0, 0, 0);
                    accN[d] = __builtin_amdgcn_mfma_f32_16x16x32_bf16(cp1, wih_f[d][1], accN[d], 0, 0, 0);
                }
            }
        }

        // issue x loads FIRST (keeps them older than this step's stores)
        {
            const int s = (LAY > 0) ? t + 3 : t + 2;
            if (s < T_) {
                if constexpr (LAY > 0) {
                    if ((s & (CP - 1)) == 0) {
                        int tgt = s + CP - 1; if (tgt > T_ - 1) tgt = T_ - 1;
                        spin_ge(progIn, tgt);
                    }
                    const char* src = (const char*)ringIn + (s & (D_RING - 1)) * SLOT_BYTES;
                    asm volatile(
                        "global_load_dwordx4 %0, %2, off sc0 sc1\n\t"
                        "global_load_dwordx4 %1, %3, off sc0 sc1"
                        : "=v"(cp0), "=v"(cp1)
                        : "v"(src + rOffA), "v"(src + rOffB)
                        : "memory");
                } else {
                    asm volatile("global_load_dwordx4 %0, %1, off"
                                 : "=v"(cur0) : "v"(xrow(s)) : "memory");
                }
            }
        }

        // ring store of h[t-1] (wave 0; values live in ha/hb). Runs at t=0
        // too (slot 63 dummy; overwritten a revolution before any read).
        if constexpr (LAY < 2) {
            if (w == 0) {
                char* dst = (char*)ringOut + ((t - 1) & (D_RING - 1)) * SLOT_BYTES;
                ring_store16(dst + rOffA, ha);
                ring_store16(dst + rOffB, hb);
            }
        }

        // cell update (lane-local: rows 4kq+r at column hdim).
        // Gates arrive PRE-SCALED (i,f,o by L2E; g by 2*L2E) -> raw exp2/rcp.
        float h[4];
        #pragma unroll
        for (int r = 0; r < 4; ++r) {
            const float gi = accC[0][r], gf = accC[1][r], gg = accC[2][r], go = accC[3][r];
            const float si = rcp_hw(1.0f + exp2_hw(-gi));
            const float sf = rcp_hw(1.0f + exp2_hw(-gf));
            const float so = rcp_hw(1.0f + exp2_hw(-go));
            const float tg = __builtin_fmaf(2.0f, rcp_hw(1.0f + exp2_hw(-gg)), -1.0f);
            c[r] = sf * c[r] + si * tg;
            const float tc = __builtin_fmaf(2.0f, rcp_hw(1.0f + exp2_hw(c[r] * (-2.0f * L2E))), -1.0f);
            h[r] = so * tc;
        }
        const unsigned p01 = cvtpk_bf16(h[0], h[1]);
        const unsigned p23 = cvtpk_bf16(h[2], h[3]);
        char* wbase = ldsb + (par << 11);
        *(unsigned short*)(wbase + wrA[0]) = (unsigned short)(p01 & 0xffff);
        *(unsigned short*)(wbase + wrA[1]) = (unsigned short)(p01 >> 16);
        *(unsigned short*)(wbase + wrA[2]) = (unsigned short)(p23 & 0xffff);
        *(unsigned short*)(wbase + wrA[3]) = (unsigned short)(p23 >> 16);
        if constexpr (LAY == 2) {
            if (t == T_ - 1) {
                #pragma unroll
                for (int r = 0; r < 4; ++r)
                    hlast[(g * 16 + kq * 4 + r) * 64 + hdim] = h[r];
            }
        }

        lds_barrier();   // h[t] visible; global ops stay in flight

        // consumption progress publish (plain store; baseline-identical)
        if constexpr (LAY > 0) {
            if (tid == 0 && (t & (CP - 1)) == CP - 1) flag_store(consInP, t);
        }
    };

    #pragma unroll 1
    for (int t = 0; t < T_ - 4; t += 2) {
        step(t,     0, false, accA, accB, curA0, curA1);
        step(t + 1, 1, false, accB, accA, curB0, curB1);
    }
    // tail: last 4 steps with full drains (load issue has stopped; counted
    // waits would under-wait)
    step(T_ - 4, 0, true, accA, accB, curA0, curA1);
    step(T_ - 3, 1, true, accB, accA, curB0, curB1);
    step(T_ - 2, 0, true, accA, accB, curA0, curA1);
    step(T_ - 1, 1, true, accB, accA, curB0, curB1);

    // ---- epilogue: publish h[T-1] + tail chunk ----
    if constexpr (LAY < 2) {
        if (w == 0) {
            const int par = (T_ - 1) & 1;
            const bf16x8 ha = *(const bf16x8*)(ldsb + (par << 11) + rdA0);
            const bf16x8 hb = *(const bf16x8*)(ldsb + (par << 11) + rdA1);
            char* dst = (char*)ringOut + ((T_ - 1) & (D_RING - 1)) * SLOT_BYTES;
            ring_store16(dst + rOffA, ha);
            ring_store16(dst + rOffB, hb);
        }
        lds_barrier();
        if (tid == 0) flag_store_drain(progOut, T_ - 1);
    }
}

__global__ __launch_bounds__(256, 1)
void lstm_pipe(const unsigned short* __restrict__ xPk,
               const unsigned short* __restrict__ wih0p,
               const unsigned short* __restrict__ wih1,
               const unsigned short* __restrict__ wih2,
               const unsigned short* __restrict__ whh0,
               const unsigned short* __restrict__ whh1,
               const unsigned short* __restrict__ whh2,
               const float* __restrict__ bih0, const float* __restrict__ bhh0,
               const float* __restrict__ bih1, const float* __restrict__ bhh1,
               const float* __restrict__ bih2, const float* __restrict__ bhh2,
               unsigned short* __restrict__ ring, int* __restrict__ flags,
               float* __restrict__ hlast)
{
    __shared__ unsigned short lds[2][1024];   // 4 KiB double-buffered h tile

    const int g   = blockIdx.x & 63;
    const int lay = blockIdx.x >> 6;

    const size_t GSHORTS = (size_t)D_RING * SLOT_BYTES / 2;     // per (iface,g)
    unsigned short* r0 = ring + ((size_t)0 * NG + g) * GSHORTS;
    unsigned short* r1 = ring + ((size_t)1 * NG + g) * GSHORTS;
    int* prog0 = flags + (0 * 64 + g) * 16;
    int* prog1 = flags + (1 * 64 + g) * 16;
    int* cons0 = flags + (128 + 0 * 64 + g) * 16;
    int* cons1 = flags + (128 + 1 * 64 + g) * 16;

    if (lay == 0) {
        pipe_body<0>(g, xPk, wih0p, whh0, bih0, bhh0,
                     nullptr, r0, nullptr, prog0, nullptr, cons0,
                     hlast, &lds[0][0]);
    } else if (lay == 1) {
        pipe_body<1>(g, xPk, wih1, whh1, bih1, bhh1,
                     r0, r1, prog0, prog1, cons0, cons1,
                     hlast, &lds[0][0]);
    } else {
        pipe_body<2>(g, xPk, wih2, whh2, bih2, bhh2,
                     r1, nullptr, prog1, nullptr, cons1, nullptr,
                     hlast, &lds[0][0]);
    }
}

// ---------------------------------------------------------------------------
// MLP head: one block per batch row. 64 -> 128 relu -> 64 relu -> 2.
// ---------------------------------------------------------------------------
__global__ __launch_bounds__(128)
void mlp_head_kernel(const float* __restrict__ hlast,
                     const float* __restrict__ fc1_w, const float* __restrict__ fc1_b,
                     const float* __restrict__ fc3_w, const float* __restrict__ fc3_b,
                     const float* __restrict__ fc2_w, const float* __restrict__ fc2_b,
                     float* __restrict__ outp)
{
    __shared__ float s_h[H_];
    __shared__ float s_z1[128];
    __shared__ float s_z3[64];
    const int b = blockIdx.x, tid = threadIdx.x;

    if (tid < H_) s_h[tid] = hlast[b * H_ + tid];
    __syncthreads();

    {
        float acc = fc1_b[tid];
        #pragma unroll
        for (int k = 0; k < H_; ++k) acc += fc1_w[tid * H_ + k] * s_h[k];
        s_z1[tid] = fmaxf(acc, 0.0f);
    }
    __syncthreads();

    if (tid < 64) {
        float acc = fc3_b[tid];
        #pragma unroll
        for (int k = 0; k < 128; ++k) acc += fc3_w[tid * 128 + k] * s_z1[k];
        s_z3[tid] = fmaxf(acc, 0.0f);
    }
    __syncthreads();

    if (tid < 2) {
        float acc = fc2_b[tid];
        #pragma unroll
        for (int k = 0; k < 64; ++k) acc += fc2_w[tid * 64 + k] * s_z3[k];
        outp[b * 2 + tid] = acc;
    }
}

} // namespace

extern "C" void kernel_launch(void* const* d_in, const int* in_sizes, int n_in,
                              void* d_out, int out_size, void* d_ws, size_t ws_size,
                              hipStream_t stream) {
    (void)in_sizes; (void)n_in; (void)out_size; (void)ws_size;

    const float* x     = (const float*)d_in[0];
    const float* wih0  = (const float*)d_in[1];
    const float* whh0  = (const float*)d_in[2];
    const float* bih0  = (const float*)d_in[3];
    const float* bhh0  = (const float*)d_in[4];
    const float* wih1  = (const float*)d_in[5];
    const float* whh1  = (const float*)d_in[6];
    const float* bih1  = (const float*)d_in[7];
    const float* bhh1  = (const float*)d_in[8];
    const float* wih2  = (const float*)d_in[9];
    const float* whh2  = (const float*)d_in[10];
    const float* bih2  = (const float*)d_in[11];
    const float* bhh2  = (const float*)d_in[12];
    const float* fc1_w = (const float*)d_in[13];
    const float* fc1_b = (const float*)d_in[14];
    const float* fc3_w = (const float*)d_in[15];
    const float* fc3_b = (const float*)d_in[16];
    const float* fc2_w = (const float*)d_in[17];
    const float* fc2_b = (const float*)d_in[18];
    float* out = (float*)d_out;

    // ---- workspace layout ----
    char* base = (char*)d_ws;
    const size_t RING_B = (size_t)2 * NG * D_RING * SLOT_BYTES;      // 16 MiB
    const size_t XPK_B  = (size_t)T_ * NG * 16 * 8 * 2;              // 8 MiB
    const size_t FLAG_B = 4096 * sizeof(int);                        // 16 KiB
    unsigned short* ring  = (unsigned short*)(base);
    unsigned short* xPk   = (unsigned short*)(base + RING_B);
    int*            flags = (int*)(base + RING_B + XPK_B);
    float*          hlast = (float*)(base + RING_B + XPK_B + FLAG_B);
    char* wp = base + RING_B + XPK_B + FLAG_B + (size_t)B_ * H_ * 4;
    unsigned short* whh_b[3];
    for (int i = 0; i < 3; ++i) { whh_b[i] = (unsigned short*)wp; wp += 256 * 64 * 2; }
    unsigned short* wih_b1 = (unsigned short*)wp; wp += 256 * 64 * 2;
    unsigned short* wih_b2 = (unsigned short*)wp; wp += 256 * 64 * 2;
    unsigned short* wih0p  = (unsigned short*)wp; wp += 256 * 8 * 2;

    // ---- setup: flags, weights (pre-scaled), packed x ----
    init_flags<<<16, 256, 0, stream>>>(flags, 4096);
    const int NW = 256 * 64;
    cvt_bf16_kernel<<<NW / 256, 256, 0, stream>>>(whh0, whh_b[0], NW);
    cvt_bf16_kernel<<<NW / 256, 256, 0, stream>>>(whh1, whh_b[1], NW);
    cvt_bf16_kernel<<<NW / 256, 256, 0, stream>>>(whh2, whh_b[2], NW);
    cvt_bf16_kernel<<<NW / 256, 256, 0, stream>>>(wih1, wih_b1, NW);
    cvt_bf16_kernel<<<NW / 256, 256, 0, stream>>>(wih2, wih_b2, NW);
    cvt_wih0_kernel<<<8, 256, 0, stream>>>(wih0, wih0p);
    build_xpk<<<(T_ * NG * 16 * 8) / 256, 256, 0, stream>>>(x, xPk);

    // ---- pipelined LSTM stack: 192 blocks (64 groups x 3 layers) ----
    lstm_pipe<<<192, 256, 0, stream>>>(xPk, wih0p, wih_b1, wih_b2,
                                       whh_b[0], whh_b[1], whh_b[2],
                                       bih0, bhh0, bih1, bhh1, bih2, bhh2,
                                       ring, flags, hlast);

    // ---- MLP head ----
    mlp_head_kernel<<<B_, 128, 0, stream>>>(hlast, fc1_w, fc1_b, fc3_w, fc3_b,
                                            fc2_w, fc2_b, out);
}

// Round 6
// 376.172 us; speedup vs baseline: 2.1093x; 1.0262x over previous
//
#include <hip/hip_runtime.h>
#include <cstdint>
#include <cstddef>

namespace {

constexpr int B_ = 1024;
constexpr int T_ = 512;
constexpr int H_ = 64;
constexpr int NG = 64;            // batch groups (16 rows each)
constexpr int D_RING = 64;        // ring depth in steps
constexpr int CP = 16;            // poll/publish chunk (baseline-proven)
constexpr int SLOT_BYTES = 16 * 64 * 2;   // one h-tile: [16 rows][64 hd] bf16

constexpr float L2E  = 1.4426950408889634f;   // log2(e)

typedef short bf16x8 __attribute__((ext_vector_type(8)));
typedef float f32x4  __attribute__((ext_vector_type(4)));

// hardware exp2 / rcp (pure, CSE-able; ~1 ulp — far inside the 2.2e-3 budget)
__device__ __forceinline__ float exp2_hw(float x) {
    float r; asm("v_exp_f32 %0, %1" : "=v"(r) : "v"(x)); return r;
}
__device__ __forceinline__ float rcp_hw(float x) {
    float r; asm("v_rcp_f32 %0, %1" : "=v"(r) : "v"(x)); return r;
}

__device__ __forceinline__ unsigned short f2bf(float f) {   // RNE fp32 -> bf16
    unsigned u = __float_as_uint(f);
    u += 0x7FFF + ((u >> 16) & 1);
    return (unsigned short)(u >> 16);
}

// packed RNE fp32x2 -> bf16x2 (low = a, high = b)
__device__ __forceinline__ unsigned cvtpk_bf16(float a, float b) {
    unsigned r;
    asm("v_cvt_pk_bf16_f32 %0, %1, %2" : "=v"(r) : "v"(a), "v"(b));
    return r;
}

// LDS-only barrier: does NOT drain vmcnt — global ops stay in flight.
__device__ __forceinline__ void lds_barrier() {
    asm volatile("s_waitcnt lgkmcnt(0)\n\ts_barrier" ::: "memory");
}

// device-coherent (sc0 sc1) 16B store: write-through -> LLC-visible
__device__ __forceinline__ void ring_store16(void* dst, bf16x8 v) {
    asm volatile("global_store_dwordx4 %0, %1, off sc0 sc1"
                 :: "v"(dst), "v"(v) : "memory");
}
// coherent flag load (bypasses stale L2) — BLOCKING
__device__ __forceinline__ int flag_load(const int* p) {
    int v;
    asm volatile("global_load_dword %0, %1, off sc0 sc1\n\t"
                 "s_waitcnt vmcnt(0)" : "=v"(v) : "v"(p) : "memory");
    return v;
}
// release flag store: drain own stores, then coherent store (producers only)
__device__ __forceinline__ void flag_store_drain(int* p, int v) {
    asm volatile("s_waitcnt vmcnt(0)\n\t"
                 "global_store_dword %0, %1, off sc0 sc1"
                 :: "v"(p), "v"(v) : "memory");
}
// plain coherent flag store (consumption progress: no drain needed)
__device__ __forceinline__ void flag_store(int* p, int v) {
    asm volatile("global_store_dword %0, %1, off sc0 sc1"
                 :: "v"(p), "v"(v) : "memory");
}
__device__ __forceinline__ void spin_ge(const int* p, int tgt) {
    while (flag_load(p) < tgt) __builtin_amdgcn_s_sleep(1);
}

// ---------------------------------------------------------------------------
// Setup kernels.  Weights/biases are PRE-SCALED: gate rows i,f,o by log2(e),
// g rows (block 2: rows 128..191) by 2*log2(e), so the cell update uses raw
// v_exp_f32 (exp2) with no per-element scaling.
// ---------------------------------------------------------------------------
__global__ void init_flags(int* p, int n) {
    int i = blockIdx.x * 256 + threadIdx.x;
    if (i < n) p[i] = -1;
}

// [256][64] fp32 -> bf16, row-dependent scale
__global__ void cvt_bf16_kernel(const float* __restrict__ src,
                                unsigned short* __restrict__ dst, int n) {
    int i = blockIdx.x * 256 + threadIdx.x;
    if (i < n) {
        int row = i >> 6;                       // gate row 0..255
        float sc = ((row >> 6) == 2) ? 2.0f * L2E : L2E;
        dst[i] = f2bf(src[i] * sc);
    }
}

// wih0: [256][6] fp32 -> [256][8] bf16 (k=6,7 zero), scaled
__global__ void cvt_wih0_kernel(const float* __restrict__ src,
                                unsigned short* __restrict__ dst) {
    int i = blockIdx.x * 256 + threadIdx.x;   // 2048
    int g = i >> 3, k = i & 7;
    float sc = ((g >> 6) == 2) ? 2.0f * L2E : L2E;
    dst[i] = (k < 6) ? f2bf(src[g * 6 + k] * sc) : (unsigned short)0;
}

// xPk[t][g][r16][k8] bf16: L0's A-frag-ready x (k 0..5 valid, 6,7 zero)
__global__ void build_xpk(const float* __restrict__ x,
                          unsigned short* __restrict__ xPk) {
    int idx = blockIdx.x * 256 + threadIdx.x;   // T*NG*16*8 = 4.19M
    int k = idx & 7, r = (idx >> 3) & 15, g = (idx >> 7) & 63, t = idx >> 13;
    float v = (k < 6) ? x[((size_t)(g * 16 + r) * T_ + t) * 6 + k] : 0.f;
    xPk[idx] = f2bf(v);
}

// ---------------------------------------------------------------------------
// Pipelined LSTM body (round-4 PASS structure; flag protocol byte-identical).
// Changes this round (both lane-local / stall-removal only):
//  1. Cell algebra: si*tg = (1-B)/((1+A)(1+B)), h = (1-C)/((1+D)(1+C)) ->
//     5 exp2 + 3 rcp per h (was 5+5). Only the C-arg (-2*L2E*c) is clamped
//     to +-80 (c is the one unbounded quantity; clamped form still yields
//     h -> +-so exactly, matching the old form's graceful inf handling).
//  2. Producer backpressure spin guarded to w==0: waves 1-3 never store the
//     ring, so their spin was a pure ~700cy LLC stall + 4x flag traffic.
// ---------------------------------------------------------------------------
template<int LAY>
__device__ __forceinline__ void pipe_body(
    int g,
    const unsigned short* __restrict__ xPk,
    const unsigned short* __restrict__ wih,
    const unsigned short* __restrict__ whh,
    const float* __restrict__ bih, const float* __restrict__ bhh,
    const unsigned short* __restrict__ ringIn, unsigned short* __restrict__ ringOut,
    const int* progIn, int* progOut, int* consInP, const int* consOutP,
    float* __restrict__ hlast, unsigned short* lds)
{
    const int tid = threadIdx.x;
    const int l   = tid & 63;
    const int w   = tid >> 6;
    const int r16 = l & 15;
    const int kq  = l >> 4;
    const int hdim = w * 16 + r16;

    // ---- weight fragments (B-frag: col=l&15 -> gate row, k=8*kq+i) ----
    bf16x8 whh_f[4][2], wih_f[4][2];
    f32x4  bias_acc[4];
    #pragma unroll
    for (int d = 0; d < 4; ++d) {
        const int gg = d * 64 + hdim;
        const float sc = (d == 2) ? 2.0f * L2E : L2E;
        const float b = (bih[gg] + bhh[gg]) * sc;
        bias_acc[d] = f32x4{b, b, b, b};
        whh_f[d][0] = *(const bf16x8*)(whh + gg * 64 + kq * 8);
        whh_f[d][1] = *(const bf16x8*)(whh + gg * 64 + 32 + kq * 8);
        if constexpr (LAY == 0) {
            bf16x8 z = {};
            wih_f[d][0] = (kq == 0) ? *(const bf16x8*)(wih + gg * 8) : z;
            wih_f[d][1] = z;
        } else {
            wih_f[d][0] = *(const bf16x8*)(wih + gg * 64 + kq * 8);
            wih_f[d][1] = *(const bf16x8*)(wih + gg * 64 + 32 + kq * 8);
        }
    }

    // ---- LDS addressing (XOR swizzle, verified r4-r9) ----
    char* ldsb = (char*)lds;
    const int rdA0 = r16 * 128 + (((0 + kq) ^ (r16 & 7)) << 4);
    const int rdA1 = r16 * 128 + (((4 + kq) ^ (r16 & 7)) << 4);
    int wrA[4];
    #pragma unroll
    for (int r = 0; r < 4; ++r) {
        const int row = 4 * kq + r;
        wrA[r] = row * 128 + (((hdim >> 3) ^ (row & 7)) << 4) + (hdim & 7) * 2;
    }
    // ring lane offsets (linear row-major inside a slot)
    const int rOffA = r16 * 128 + kq * 16;
    const int rOffB = r16 * 128 + 64 + kq * 16;

    // L0 xPk row address (wave-wide; lanes sharing r16 read the same 16B)
    auto xrow = [&](int t) -> const char* {
        return (const char*)xPk + (((size_t)t * NG + g) * 16 + r16) * 16;
    };

    // ---- zero LDS (h[-1]=0), init cell state ----
    ((uint4*)ldsb)[tid] = make_uint4(0, 0, 0, 0);   // 256*16B = 4 KiB
    float c[4] = {0.f, 0.f, 0.f, 0.f};
    lds_barrier();

    // ---- ramp ----
    bf16x8 cur0 = {};                       // LAY0 x register
    bf16x8 curA0 = {}, curA1 = {};          // LAY>0 parity-0 x regs
    bf16x8 curB0 = {}, curB1 = {};          // LAY>0 parity-1 x regs
    f32x4 accA[4], accB[4];
    {
        bf16x8 x0a = {}, x0b = {};
        if constexpr (LAY > 0) {
            spin_ge(progIn, (CP - 1 < T_ - 1) ? CP - 1 : T_ - 1);
            const char* s0 = (const char*)ringIn;                     // slot 0
            const char* s1 = (const char*)ringIn + SLOT_BYTES;        // slot 1
            const char* s2 = (const char*)ringIn + 2 * SLOT_BYTES;    // slot 2
            asm volatile(
                "global_load_dwordx4 %0, %6, off sc0 sc1\n\t"
                "global_load_dwordx4 %1, %7, off sc0 sc1\n\t"
                "global_load_dwordx4 %2, %8, off sc0 sc1\n\t"
                "global_load_dwordx4 %3, %9, off sc0 sc1\n\t"
                "global_load_dwordx4 %4, %10, off sc0 sc1\n\t"
                "global_load_dwordx4 %5, %11, off sc0 sc1\n\t"
                "s_waitcnt vmcnt(0)"
                : "=v"(x0a), "=v"(x0b), "=v"(curA0), "=v"(curA1),
                  "=v"(curB0), "=v"(curB1)
                : "v"(s0 + rOffA), "v"(s0 + rOffB),
                  "v"(s1 + rOffA), "v"(s1 + rOffB),
                  "v"(s2 + rOffA), "v"(s2 + rOffB)
                : "memory");
            __builtin_amdgcn_sched_barrier(0);
        } else {
            asm volatile(
                "global_load_dwordx4 %0, %2, off\n\t"
                "global_load_dwordx4 %1, %3, off\n\t"
                "s_waitcnt vmcnt(0)"
                : "=v"(x0a), "=v"(cur0)
                : "v"(xrow(0)), "v"(xrow(1))
                : "memory");
            __builtin_amdgcn_sched_barrier(0);
        }
        #pragma unroll
        for (int d = 0; d < 4; ++d) {
            accA[d] = __builtin_amdgcn_mfma_f32_16x16x32_bf16(x0a, wih_f[d][0], bias_acc[d], 0, 0, 0);
            if constexpr (LAY != 0)
                accA[d] = __builtin_amdgcn_mfma_f32_16x16x32_bf16(x0b, wih_f[d][1], accA[d], 0, 0, 0);
        }
    }

    // ---- one step ----
    auto step = [&](int t, int par, bool tail, f32x4* accC, f32x4* accN,
                    bf16x8& cp0, bf16x8& cp1) {
        // producer backpressure (chunk edge; w0 only — the sole ring-storer)
        if constexpr (LAY < 2) {
            if (w == 0 && (t & (CP - 1)) == 0) spin_ge(consOutP, t + CP - D_RING);
        }
        // early publish (baseline-identical: drained release, cadence 16)
        if constexpr (LAY < 2) {
            if ((t & (CP - 1)) == 1 && t > 1) {
                if (tid == 0) flag_store_drain(progOut, t - 2);
            }
        }

        // h[t-1] A-frags from LDS
        const bf16x8 ha = *(const bf16x8*)(ldsb + ((par ^ 1) << 11) + rdA0);
        const bf16x8 hb = *(const bf16x8*)(ldsb + ((par ^ 1) << 11) + rdA1);

        // h-part MFMAs (critical chain)
        #pragma unroll
        for (int d = 0; d < 4; ++d) {
            accC[d] = __builtin_amdgcn_mfma_f32_16x16x32_bf16(ha, whh_f[d][0], accC[d], 0, 0, 0);
            accC[d] = __builtin_amdgcn_mfma_f32_16x16x32_bf16(hb, whh_f[d][1], accC[d], 0, 0, 0);
        }

        // wait for x(t+1) regs (derivation in round-4 header; unchanged)
        if (tail) {
            asm volatile("s_waitcnt vmcnt(0)" ::: "memory");
        } else if constexpr (LAY == 0) {
            if (w == 0) asm volatile("s_waitcnt vmcnt(2)" ::: "memory");
            else        asm volatile("s_waitcnt vmcnt(0)" ::: "memory");
        } else if constexpr (LAY == 1) {
            if (w == 0) asm volatile("s_waitcnt vmcnt(6)" ::: "memory");
            else        asm volatile("s_waitcnt vmcnt(2)" ::: "memory");
        } else {
            asm volatile("s_waitcnt vmcnt(2)" ::: "memory");
        }
        __builtin_amdgcn_sched_barrier(0);

        // x-part of t+1 into accN (off-chain; overlaps cell update)
        if (t + 1 < T_) {
            if constexpr (LAY == 0) {
                #pragma unroll
                for (int d = 0; d < 4; ++d)
                    accN[d] = __builtin_amdgcn_mfma_f32_16x16x32_bf16(cur0, wih_f[d][0], bias_acc[d], 0, 0, 0);
            } else {
                #pragma unroll
                for (int d = 0; d < 4; ++d) {
                    accN[d] = __builtin_amdgcn_mfma_f32_16x16x32_bf16(cp0, wih_f[d][0], bias_acc[d], 0, 0, 0);
                    accN[d] = __builtin_amdgcn_mfma_f32_16x16x32_bf16(cp1, wih_f[d][1], accN[d], 0, 0, 0);
                }
            }
        }

        // issue x loads FIRST (keeps them older than this step's stores)
        {
            const int s = (LAY > 0) ? t + 3 : t + 2;
            if (s < T_) {
                if constexpr (LAY > 0) {
                    if ((s & (CP - 1)) == 0) {
                        int tgt = s + CP - 1; if (tgt > T_ - 1) tgt = T_ - 1;
                        spin_ge(progIn, tgt);
                    }
                    const char* src = (const char*)ringIn + (s & (D_RING - 1)) * SLOT_BYTES;
                    asm volatile(
                        "global_load_dwordx4 %0, %2, off sc0 sc1\n\t"
                        "global_load_dwordx4 %1, %3, off sc0 sc1"
                        : "=v"(cp0), "=v"(cp1)
                        : "v"(src + rOffA), "v"(src + rOffB)
                        : "memory");
                } else {
                    asm volatile("global_load_dwordx4 %0, %1, off"
                                 : "=v"(cur0) : "v"(xrow(s)) : "memory");
                }
            }
        }

        // ring store of h[t-1] (wave 0; values live in ha/hb). Runs at t=0
        // too (slot 63 dummy; overwritten a revolution before any read).
        if constexpr (LAY < 2) {
            if (w == 0) {
                char* dst = (char*)ringOut + ((t - 1) & (D_RING - 1)) * SLOT_BYTES;
                ring_store16(dst + rOffA, ha);
                ring_store16(dst + rOffB, hb);
            }
        }

        // cell update (lane-local: rows 4kq+r at column hdim).
        // Gates PRE-SCALED (i,f,o by L2E; g by 2*L2E). Reduced-trans form:
        //   si*tg = (1-B)/((1+A)(1+B));  sf = rcp(1+F)
        //   h = so*tanh(c) = (1-C)/((1+D)(1+C)),  C-arg clamped to +-80
        // (A,B,D,F are bounded by the |gate|<=~24 hard bound; only c is
        //  unbounded -> only C needs the clamp. Clamped tails give h=+-so
        //  exactly, matching the old form's graceful inf handling.)
        float h[4];
        #pragma unroll
        for (int r = 0; r < 4; ++r) {
            const float gi = accC[0][r], gf = accC[1][r], gg = accC[2][r], go = accC[3][r];
            const float A  = exp2_hw(-gi);
            const float F  = exp2_hw(-gf);
            const float Bx = exp2_hw(-gg);
            const float D  = exp2_hw(-go);
            const float r1 = rcp_hw((1.0f + A) * (1.0f + Bx));
            const float r2 = rcp_hw(1.0f + F);
            c[r] = __builtin_fmaf(c[r], r2, (1.0f - Bx) * r1);
            float ca = c[r] * (-2.0f * L2E);
            ca = fminf(fmaxf(ca, -80.0f), 80.0f);
            const float C  = exp2_hw(ca);
            const float r3 = rcp_hw((1.0f + D) * (1.0f + C));
            h[r] = (1.0f - C) * r3;
        }
        const unsigned p01 = cvtpk_bf16(h[0], h[1]);
        const unsigned p23 = cvtpk_bf16(h[2], h[3]);
        char* wbase = ldsb + (par << 11);
        *(unsigned short*)(wbase + wrA[0]) = (unsigned short)(p01 & 0xffff);
        *(unsigned short*)(wbase + wrA[1]) = (unsigned short)(p01 >> 16);
        *(unsigned short*)(wbase + wrA[2]) = (unsigned short)(p23 & 0xffff);
        *(unsigned short*)(wbase + wrA[3]) = (unsigned short)(p23 >> 16);
        if constexpr (LAY == 2) {
            if (t == T_ - 1) {
                #pragma unroll
                for (int r = 0; r < 4; ++r)
                    hlast[(g * 16 + kq * 4 + r) * 64 + hdim] = h[r];
            }
        }

        lds_barrier();   // h[t] visible; global ops stay in flight

        // consumption progress publish (plain store; baseline-identical)
        if constexpr (LAY > 0) {
            if (tid == 0 && (t & (CP - 1)) == CP - 1) flag_store(consInP, t);
        }
    };

    #pragma unroll 1
    for (int t = 0; t < T_ - 4; t += 2) {
        step(t,     0, false, accA, accB, curA0, curA1);
        step(t + 1, 1, false, accB, accA, curB0, curB1);
    }
    // tail: last 4 steps with full drains (load issue has stopped; counted
    // waits would under-wait)
    step(T_ - 4, 0, true, accA, accB, curA0, curA1);
    step(T_ - 3, 1, true, accB, accA, curB0, curB1);
    step(T_ - 2, 0, true, accA, accB, curA0, curA1);
    step(T_ - 1, 1, true, accB, accA, curB0, curB1);

    // ---- epilogue: publish h[T-1] + tail chunk ----
    if constexpr (LAY < 2) {
        if (w == 0) {
            const int par = (T_ - 1) & 1;
            const bf16x8 ha = *(const bf16x8*)(ldsb + (par << 11) + rdA0);
            const bf16x8 hb = *(const bf16x8*)(ldsb + (par << 11) + rdA1);
            char* dst = (char*)ringOut + ((T_ - 1) & (D_RING - 1)) * SLOT_BYTES;
            ring_store16(dst + rOffA, ha);
            ring_store16(dst + rOffB, hb);
        }
        lds_barrier();
        if (tid == 0) flag_store_drain(progOut, T_ - 1);
    }
}

__global__ __launch_bounds__(256, 1)
void lstm_pipe(const unsigned short* __restrict__ xPk,
               const unsigned short* __restrict__ wih0p,
               const unsigned short* __restrict__ wih1,
               const unsigned short* __restrict__ wih2,
               const unsigned short* __restrict__ whh0,
               const unsigned short* __restrict__ whh1,
               const unsigned short* __restrict__ whh2,
               const float* __restrict__ bih0, const float* __restrict__ bhh0,
               const float* __restrict__ bih1, const float* __restrict__ bhh1,
               const float* __restrict__ bih2, const float* __restrict__ bhh2,
               unsigned short* __restrict__ ring, int* __restrict__ flags,
               float* __restrict__ hlast)
{
    __shared__ unsigned short lds[2][1024];   // 4 KiB double-buffered h tile

    const int g   = blockIdx.x & 63;
    const int lay = blockIdx.x >> 6;

    const size_t GSHORTS = (size_t)D_RING * SLOT_BYTES / 2;     // per (iface,g)
    unsigned short* r0 = ring + ((size_t)0 * NG + g) * GSHORTS;
    unsigned short* r1 = ring + ((size_t)1 * NG + g) * GSHORTS;
    int* prog0 = flags + (0 * 64 + g) * 16;
    int* prog1 = flags + (1 * 64 + g) * 16;
    int* cons0 = flags + (128 + 0 * 64 + g) * 16;
    int* cons1 = flags + (128 + 1 * 64 + g) * 16;

    if (lay == 0) {
        pipe_body<0>(g, xPk, wih0p, whh0, bih0, bhh0,
                     nullptr, r0, nullptr, prog0, nullptr, cons0,
                     hlast, &lds[0][0]);
    } else if (lay == 1) {
        pipe_body<1>(g, xPk, wih1, whh1, bih1, bhh1,
                     r0, r1, prog0, prog1, cons0, cons1,
                     hlast, &lds[0][0]);
    } else {
        pipe_body<2>(g, xPk, wih2, whh2, bih2, bhh2,
                     r1, nullptr, prog1, nullptr, cons1, nullptr,
                     hlast, &lds[0][0]);
    }
}

// ---------------------------------------------------------------------------
// MLP head: one block per batch row. 64 -> 128 relu -> 64 relu -> 2.
// ---------------------------------------------------------------------------
__global__ __launch_bounds__(128)
void mlp_head_kernel(const float* __restrict__ hlast,
                     const float* __restrict__ fc1_w, const float* __restrict__ fc1_b,
                     const float* __restrict__ fc3_w, const float* __restrict__ fc3_b,
                     const float* __restrict__ fc2_w, const float* __restrict__ fc2_b,
                     float* __restrict__ outp)
{
    __shared__ float s_h[H_];
    __shared__ float s_z1[128];
    __shared__ float s_z3[64];
    const int b = blockIdx.x, tid = threadIdx.x;

    if (tid < H_) s_h[tid] = hlast[b * H_ + tid];
    __syncthreads();

    {
        float acc = fc1_b[tid];
        #pragma unroll
        for (int k = 0; k < H_; ++k) acc += fc1_w[tid * H_ + k] * s_h[k];
        s_z1[tid] = fmaxf(acc, 0.0f);
    }
    __syncthreads();

    if (tid < 64) {
        float acc = fc3_b[tid];
        #pragma unroll
        for (int k = 0; k < 128; ++k) acc += fc3_w[tid * 128 + k] * s_z1[k];
        s_z3[tid] = fmaxf(acc, 0.0f);
    }
    __syncthreads();

    if (tid < 2) {
        float acc = fc2_b[tid];
        #pragma unroll
        for (int k = 0; k < 64; ++k) acc += fc2_w[tid * 64 + k] * s_z3[k];
        outp[b * 2 + tid] = acc;
    }
}

} // namespace

extern "C" void kernel_launch(void* const* d_in, const int* in_sizes, int n_in,
                              void* d_out, int out_size, void* d_ws, size_t ws_size,
                              hipStream_t stream) {
    (void)in_sizes; (void)n_in; (void)out_size; (void)ws_size;

    const float* x     = (const float*)d_in[0];
    const float* wih0  = (const float*)d_in[1];
    const float* whh0  = (const float*)d_in[2];
    const float* bih0  = (const float*)d_in[3];
    const float* bhh0  = (const float*)d_in[4];
    const float* wih1  = (const float*)d_in[5];
    const float* whh1  = (const float*)d_in[6];
    const float* bih1  = (const float*)d_in[7];
    const float* bhh1  = (const float*)d_in[8];
    const float* wih2  = (const float*)d_in[9];
    const float* whh2  = (const float*)d_in[10];
    const float* bih2  = (const float*)d_in[11];
    const float* bhh2  = (const float*)d_in[12];
    const float* fc1_w = (const float*)d_in[13];
    const float* fc1_b = (const float*)d_in[14];
    const float* fc3_w = (const float*)d_in[15];
    const float* fc3_b = (const float*)d_in[16];
    const float* fc2_w = (const float*)d_in[17];
    const float* fc2_b = (const float*)d_in[18];
    float* out = (float*)d_out;

    // ---- workspace layout ----
    char* base = (char*)d_ws;
    const size_t RING_B = (size_t)2 * NG * D_RING * SLOT_BYTES;      // 16 MiB
    const size_t XPK_B  = (size_t)T_ * NG * 16 * 8 * 2;              // 8 MiB
    const size_t FLAG_B = 4096 * sizeof(int);                        // 16 KiB
    unsigned short* ring  = (unsigned short*)(base);
    unsigned short* xPk   = (unsigned short*)(base + RING_B);
    int*            flags = (int*)(base + RING_B + XPK_B);
    float*          hlast = (float*)(base + RING_B + XPK_B + FLAG_B);
    char* wp = base + RING_B + XPK_B + FLAG_B + (size_t)B_ * H_ * 4;
    unsigned short* whh_b[3];
    for (int i = 0; i < 3; ++i) { whh_b[i] = (unsigned short*)wp; wp += 256 * 64 * 2; }
    unsigned short* wih_b1 = (unsigned short*)wp; wp += 256 * 64 * 2;
    unsigned short* wih_b2 = (unsigned short*)wp; wp += 256 * 64 * 2;
    unsigned short* wih0p  = (unsigned short*)wp; wp += 256 * 8 * 2;

    // ---- setup: flags, weights (pre-scaled), packed x ----
    init_flags<<<16, 256, 0, stream>>>(flags, 4096);
    const int NW = 256 * 64;
    cvt_bf16_kernel<<<NW / 256, 256, 0, stream>>>(whh0, whh_b[0], NW);
    cvt_bf16_kernel<<<NW / 256, 256, 0, stream>>>(whh1, whh_b[1], NW);
    cvt_bf16_kernel<<<NW / 256, 256, 0, stream>>>(whh2, whh_b[2], NW);
    cvt_bf16_kernel<<<NW / 256, 256, 0, stream>>>(wih1, wih_b1, NW);
    cvt_bf16_kernel<<<NW / 256, 256, 0, stream>>>(wih2, wih_b2, NW);
    cvt_wih0_kernel<<<8, 256, 0, stream>>>(wih0, wih0p);
    build_xpk<<<(T_ * NG * 16 * 8) / 256, 256, 0, stream>>>(x, xPk);

    // ---- pipelined LSTM stack: 192 blocks (64 groups x 3 layers) ----
    lstm_pipe<<<192, 256, 0, stream>>>(xPk, wih0p, wih_b1, wih_b2,
                                       whh_b[0], whh_b[1], whh_b[2],
                                       bih0, bhh0, bih1, bhh1, bih2, bhh2,
                                       ring, flags, hlast);

    // ---- MLP head ----
    mlp_head_kernel<<<B_, 128, 0, stream>>>(hlast, fc1_w, fc1_b, fc3_w, fc3_b,
                                            fc2_w, fc2_b, out);
}